// Round 1
// baseline (472.403 us; speedup 1.0000x reference)
//
#include <hip/hip_runtime.h>

#define NT 65536
#define DM 256
#define NE 32

typedef __attribute__((ext_vector_type(8))) short v8bf;
typedef __attribute__((ext_vector_type(4))) float v4f;

// ctrl block offsets (ints)
#define C_RISKY 0
#define C_TC1 1
#define C_TC2 2
#define C_HIST1 8
#define C_HIST2 40
#define C_CUR1 72
#define C_CUR2 104

__device__ __forceinline__ unsigned short f2bf(float f) {
  union { float f; unsigned u; } v; v.f = f;
  unsigned r = v.u + 0x7FFFu + ((v.u >> 16) & 1u);  // RNE
  return (unsigned short)(r >> 16);
}

// Build combined gate weights wgn[k][e] (e<32: Wg, else Wnoise), fp32 copy.
__global__ __launch_bounds__(256) void prep_w(const float* __restrict__ Wg,
                                              const float* __restrict__ Wn,
                                              float* __restrict__ wgn) {
  int i = blockIdx.x * 256 + threadIdx.x;
  if (i < 256 * 64) {
    int k = i >> 6, e = i & 63;
    wgn[i] = (e < 32) ? Wg[k * 32 + e] : Wn[k * 32 + (e - 32)];
  }
}

// WeT[e][h][d] = bf16(We[e][d][h]) — K-contiguous B^T layout for MFMA B-frags.
__global__ __launch_bounds__(256) void prep_wet(const float* __restrict__ We,
                                                unsigned short* __restrict__ WeT) {
  __shared__ float t[32][33];
  int e = blockIdx.x;
  int d0 = (blockIdx.y >> 3) * 32, h0 = (blockIdx.y & 7) * 32;
  int tx = threadIdx.x & 31, ty = threadIdx.x >> 5;
  const float* src = We + ((size_t)e * 256 + d0) * 256 + h0;
#pragma unroll
  for (int r = 0; r < 4; ++r) t[ty + r * 8][tx] = src[(size_t)(ty + r * 8) * 256 + tx];
  __syncthreads();
  unsigned short* dst = WeT + ((size_t)e * 256 + h0) * 256 + d0;
#pragma unroll
  for (int r = 0; r < 4; ++r) dst[(size_t)(ty + r * 8) * 256 + tx] = f2bf(t[tx][ty + r * 8]);
}

// Gating: H = xWg + nv*softplus(xWn), fp32; top-2 + weights; margin-flag risky.
// Lane e in [0,64): combined output column. Wave handles 16 tokens.
__global__ __launch_bounds__(256) void gate_kernel(const float* __restrict__ x,
                                                   const float* __restrict__ wgn,
                                                   const float* __restrict__ nvec,
                                                   int4* __restrict__ records,
                                                   int* __restrict__ risky,
                                                   int* __restrict__ ctrl,
                                                   unsigned short* __restrict__ xbf,
                                                   int use_xbf) {
  __shared__ int lh[64];
  int tid = threadIdx.x;
  if (tid < 64) lh[tid] = 0;
  int bbase = blockIdx.x * 64;  // 64 tokens per block
  if (use_xbf) {               // side output: bf16 copy of x for the MFMA passes
    const float4* x4 = (const float4*)x + (size_t)bbase * 64;
    ushort4* o4 = (ushort4*)xbf + (size_t)bbase * 64;
    for (int i = tid; i < 64 * 64; i += 256) {
      float4 v = x4[i];
      ushort4 b;
      b.x = f2bf(v.x); b.y = f2bf(v.y); b.z = f2bf(v.z); b.w = f2bf(v.w);
      o4[i] = b;
    }
  }
  __syncthreads();
  int lane = tid & 63;
  int wv = __builtin_amdgcn_readfirstlane(tid >> 6);
  float nv = nvec[lane & 31];
  int t0 = bbase + wv * 16;
  const float4* xr4 = (const float4*)(x + (size_t)t0 * 256);
  float acc[16];
#pragma unroll
  for (int j = 0; j < 16; ++j) acc[j] = 0.f;
  for (int kc = 0; kc < 64; ++kc) {  // 4 K-dims per iter
    float w0 = wgn[(kc * 4 + 0) * 64 + lane];
    float w1 = wgn[(kc * 4 + 1) * 64 + lane];
    float w2 = wgn[(kc * 4 + 2) * 64 + lane];
    float w3 = wgn[(kc * 4 + 3) * 64 + lane];
#pragma unroll
    for (int j = 0; j < 16; ++j) {
      float4 xv = xr4[j * 64 + kc];  // wave-uniform address -> s_load
      acc[j] = fmaf(w0, xv.x, acc[j]);
      acc[j] = fmaf(w1, xv.y, acc[j]);
      acc[j] = fmaf(w2, xv.z, acc[j]);
      acc[j] = fmaf(w3, xv.w, acc[j]);
    }
  }
  for (int j = 0; j < 16; ++j) {
    float gv = acc[j];
    float sv = __shfl(gv, lane + 32);  // noise column for lane<32
    float H;
    if (lane < 32) {
      float sp = fmaxf(sv, 0.f) + log1pf(expf(-fabsf(sv)));  // stable softplus
      H = gv + nv * sp;
    } else
      H = -3.0e38f;
    // top-1
    float v = H; int idx = lane;
#pragma unroll
    for (int off = 32; off >= 1; off >>= 1) {
      float ov = __shfl_xor(v, off); int oi = __shfl_xor(idx, off);
      if (ov > v || (ov == v && oi < idx)) { v = ov; idx = oi; }
    }
    int i1 = idx; float v1 = v;
    // top-2
    v = (lane == i1) ? -3.0e38f : H; idx = lane;
#pragma unroll
    for (int off = 32; off >= 1; off >>= 1) {
      float ov = __shfl_xor(v, off); int oi = __shfl_xor(idx, off);
      if (ov > v || (ov == v && oi < idx)) { v = ov; idx = oi; }
    }
    int i2 = idx; float v2 = v;
    // top-3 value (margin check only)
    v = (lane == i1 || lane == i2) ? -3.0e38f : H; idx = lane;
#pragma unroll
    for (int off = 32; off >= 1; off >>= 1) {
      float ov = __shfl_xor(v, off); int oi = __shfl_xor(idx, off);
      if (ov > v || (ov == v && oi < idx)) { v = ov; idx = oi; }
    }
    float v3 = v;
    if (lane == 0) {
      float w1v = 1.f / (1.f + expf(v2 - v1));
      float w2v = 1.f / (1.f + expf(v1 - v2));
      int t = t0 + j;
      records[t] = make_int4(i1, i2, __float_as_int(w1v), __float_as_int(w2v));
      atomicAdd(&lh[i1], 1);
      atomicAdd(&lh[32 + i2], 1);
      if (v2 - v3 < 1e-3f) {  // near-tie at the 2/3 boundary: fp64 recheck
        int p = atomicAdd(&ctrl[C_RISKY], 1);
        risky[p] = t;
      }
    }
  }
  __syncthreads();
  if (tid < 32) atomicAdd(&ctrl[C_HIST1 + tid], lh[tid]);
  else if (tid < 64) atomicAdd(&ctrl[C_HIST2 + (tid - 32)], lh[tid]);
}

// fp64 recompute of gating for risky tokens; patches records + histograms.
__global__ __launch_bounds__(64) void fixup_kernel(const float* __restrict__ x,
                                                   const float* __restrict__ wgn,
                                                   const float* __restrict__ nvec,
                                                   int4* __restrict__ records,
                                                   const int* __restrict__ risky,
                                                   int* __restrict__ ctrl) {
  int cnt = ctrl[C_RISKY];
  int lane = threadIdx.x;
  for (int r = blockIdx.x; r < cnt; r += gridDim.x) {
    int t = __builtin_amdgcn_readfirstlane(risky[r]);
    const float* xr = x + (size_t)t * 256;
    double acc = 0.0;
    for (int k = 0; k < 256; ++k)
      acc = fma((double)xr[k], (double)wgn[k * 64 + lane], acc);
    double sv = __shfl(acc, lane + 32);
    double H;
    if (lane < 32) {
      double sp = fmax(sv, 0.0) + log1p(exp(-fabs(sv)));
      H = acc + (double)nvec[lane] * sp;
    } else
      H = -1e300;
    double v = H; int idx = lane;
#pragma unroll
    for (int off = 32; off >= 1; off >>= 1) {
      double ov = __shfl_xor(v, off); int oi = __shfl_xor(idx, off);
      if (ov > v || (ov == v && oi < idx)) { v = ov; idx = oi; }
    }
    int i1 = idx; double v1 = v;
    v = (lane == i1) ? -1e300 : H; idx = lane;
#pragma unroll
    for (int off = 32; off >= 1; off >>= 1) {
      double ov = __shfl_xor(v, off); int oi = __shfl_xor(idx, off);
      if (ov > v || (ov == v && oi < idx)) { v = ov; idx = oi; }
    }
    int i2 = idx; double v2 = v;
    if (lane == 0) {
      float w1v = (float)(1.0 / (1.0 + exp(v2 - v1)));
      float w2v = (float)(1.0 / (1.0 + exp(v1 - v2)));
      int4 old = records[t];
      if (old.x != i1) { atomicSub(&ctrl[C_HIST1 + old.x], 1); atomicAdd(&ctrl[C_HIST1 + i1], 1); }
      if (old.y != i2) { atomicSub(&ctrl[C_HIST2 + old.y], 1); atomicAdd(&ctrl[C_HIST2 + i2], 1); }
      records[t] = make_int4(i1, i2, __float_as_int(w1v), __float_as_int(w2v));
    }
  }
}

// Segment offsets + per-tile work tables (BM=128 tiles per expert segment).
__global__ __launch_bounds__(64) void scan_kernel(int* __restrict__ ctrl,
                                                  int4* __restrict__ table1,
                                                  int4* __restrict__ table2) {
  __shared__ int so1[32], so2[32], tp1[32], tp2[32];
  int tid = threadIdx.x;
  if (tid == 0) {
    int o = 0, tp = 0;
    for (int e = 0; e < 32; ++e) {
      so1[e] = o; tp1[e] = tp;
      int c = ctrl[C_HIST1 + e];
      o += c; tp += (c + 127) >> 7;
    }
    ctrl[C_TC1] = tp;
    o = 0; tp = 0;
    for (int e = 0; e < 32; ++e) {
      so2[e] = o; tp2[e] = tp;
      int c = ctrl[C_HIST2 + e];
      o += c; tp += (c + 127) >> 7;
    }
    ctrl[C_TC2] = tp;
  }
  __syncthreads();
  if (tid < 32) {
    int e = tid;
    ctrl[C_CUR1 + e] = so1[e];
    int c = ctrl[C_HIST1 + e];
    int nt = (c + 127) >> 7;
    for (int m = 0; m < nt; ++m)
      table1[tp1[e] + m] = make_int4(e, so1[e] + m * 128, min(128, c - m * 128), 0);
  } else {
    int e = tid - 32;
    ctrl[C_CUR2 + e] = so2[e];
    int c = ctrl[C_HIST2 + e];
    int nt = (c + 127) >> 7;
    for (int m = 0; m < nt; ++m)
      table2[tp2[e] + m] = make_int4(e, so2[e] + m * 128, min(128, c - m * 128), 0);
  }
}

// Bucket tokens by expert (stable-enough order; intra-block rank + block base).
__global__ __launch_bounds__(256) void scatter_kernel(const int4* __restrict__ records,
                                                      int* __restrict__ ctrl,
                                                      int* __restrict__ perm1, float* __restrict__ pw1,
                                                      int* __restrict__ perm2, float* __restrict__ pw2) {
  __shared__ int lh1[32], lh2[32], b1[32], b2[32];
  int tid = threadIdx.x;
  if (tid < 32) { lh1[tid] = 0; lh2[tid] = 0; }
  __syncthreads();
  int t = blockIdx.x * 256 + tid;
  int4 rec = records[t];
  int r1 = atomicAdd(&lh1[rec.x], 1);
  int r2 = atomicAdd(&lh2[rec.y], 1);
  __syncthreads();
  if (tid < 32) {
    b1[tid] = atomicAdd(&ctrl[C_CUR1 + tid], lh1[tid]);
    b2[tid] = atomicAdd(&ctrl[C_CUR2 + tid], lh2[tid]);
  }
  __syncthreads();
  int s1 = b1[rec.x] + r1; perm1[s1] = t; pw1[s1] = __int_as_float(rec.z);
  int s2 = b2[rec.y] + r2; perm2[s2] = t; pw2[s2] = __int_as_float(rec.w);
}

// Grouped GEMM: out[tok,:] (+)= w * (x[tok,:] @ We[e]) + w*be[e,:], bf16 MFMA.
// BM=128 (slots), BN=128, BK=64; 4 waves, wave-tile 64x64, 16x16x32 frags.
__global__ __launch_bounds__(256) void expert_kernel(const float* __restrict__ x,
                                                     const unsigned short* __restrict__ xbf,
                                                     int use_xbf,
                                                     const unsigned short* __restrict__ WeT,
                                                     const float* __restrict__ be,
                                                     const int* __restrict__ perm,
                                                     const float* __restrict__ pw,
                                                     const int4* __restrict__ table,
                                                     const int* __restrict__ tcp,
                                                     float* __restrict__ out,
                                                     int accumulate) {
  int nt = *tcp;
  if (blockIdx.x >= nt) return;
  int4 ent = table[blockIdx.x];
  int e = ent.x, sbase = ent.y, rows = ent.z;
  int n0 = blockIdx.y * 128;
  __shared__ __align__(16) short Al[128 * 72];  // [row][k], stride 72 (2-way bank only)
  __shared__ __align__(16) short Bl[128 * 72];  // [col][k] (B^T)
  __shared__ int toks[128];
  int tid = threadIdx.x;
  if (tid < 128) toks[tid] = perm[sbase + min(tid, rows - 1)];
  v4f acc[4][4];
  v4f zero = {0.f, 0.f, 0.f, 0.f};
#pragma unroll
  for (int mi = 0; mi < 4; ++mi)
#pragma unroll
    for (int ni = 0; ni < 4; ++ni) acc[mi][ni] = zero;
  int lane = tid & 63, wid = tid >> 6;
  int wm = (wid & 1) * 64, wn = (wid >> 1) * 64;
  int lm = lane & 15, lk = (lane >> 4) * 8;
  for (int k0 = 0; k0 < 256; k0 += 64) {
    __syncthreads();
#pragma unroll
    for (int j = 0; j < 4; ++j) {
      int idx = tid + 256 * j;           // 1024 16B chunks
      int row = idx >> 3, kc = idx & 7;  // 8 chunks per row
      if (use_xbf) {
        uint4 v = *(const uint4*)(xbf + ((size_t)toks[row] * 256 + k0 + kc * 8));
        *(uint4*)(Al + row * 72 + kc * 8) = v;
      } else {
        const float4* s = (const float4*)(x + ((size_t)toks[row] * 256 + k0 + kc * 8));
        float4 a = s[0], b = s[1];
        union { v8bf v; unsigned short u[8]; } p;
        p.u[0] = f2bf(a.x); p.u[1] = f2bf(a.y); p.u[2] = f2bf(a.z); p.u[3] = f2bf(a.w);
        p.u[4] = f2bf(b.x); p.u[5] = f2bf(b.y); p.u[6] = f2bf(b.z); p.u[7] = f2bf(b.w);
        *(v8bf*)(Al + row * 72 + kc * 8) = p.v;
      }
      uint4 w = *(const uint4*)(WeT + (((size_t)e * 256 + n0 + row) * 256 + k0 + kc * 8));
      *(uint4*)(Bl + row * 72 + kc * 8) = w;
    }
    __syncthreads();
#pragma unroll
    for (int ks = 0; ks < 64; ks += 32) {
      v8bf af[4], bfr[4];
#pragma unroll
      for (int mi = 0; mi < 4; ++mi)
        af[mi] = *(const v8bf*)(Al + (wm + mi * 16 + lm) * 72 + ks + lk);
#pragma unroll
      for (int ni = 0; ni < 4; ++ni)
        bfr[ni] = *(const v8bf*)(Bl + (wn + ni * 16 + lm) * 72 + ks + lk);
#pragma unroll
      for (int mi = 0; mi < 4; ++mi)
#pragma unroll
        for (int ni = 0; ni < 4; ++ni)
          acc[mi][ni] = __builtin_amdgcn_mfma_f32_16x16x32_bf16(af[mi], bfr[ni], acc[mi][ni], 0, 0, 0);
    }
  }
  // epilogue: C/D layout col=lane&15, row=(lane>>4)*4+reg
  int cg = lane & 15, rg = lane >> 4;
#pragma unroll
  for (int mi = 0; mi < 4; ++mi) {
#pragma unroll
    for (int r = 0; r < 4; ++r) {
      int srow = wm + mi * 16 + rg * 4 + r;
      if (srow < rows) {
        int slot = sbase + srow;
        int tok = perm[slot];
        float w = pw[slot];
        size_t ob = (size_t)tok * 256;
#pragma unroll
        for (int ni = 0; ni < 4; ++ni) {
          int c = n0 + wn + ni * 16 + cg;
          float v = acc[mi][ni][r] * w + w * be[e * 256 + c];
          if (accumulate) out[ob + c] += v;
          else out[ob + c] = v;
        }
      }
    }
  }
}

extern "C" void kernel_launch(void* const* d_in, const int* in_sizes, int n_in,
                              void* d_out, int out_size, void* d_ws, size_t ws_size,
                              hipStream_t stream) {
  const float* x = (const float*)d_in[0];
  const float* Wg = (const float*)d_in[1];
  const float* Wn = (const float*)d_in[2];
  const float* We = (const float*)d_in[3];
  const float* be = (const float*)d_in[4];
  const float* nvec = (const float*)d_in[5];
  // d_in[6] = top_k (always 2 here)
  float* out = (float*)d_out;
  char* ws = (char*)d_ws;
  size_t off = 0;
  auto alloc = [&](size_t bytes) -> void* {
    void* p = ws + off;
    off = (off + bytes + 255) & ~(size_t)255;
    return p;
  };
  int* ctrl = (int*)alloc(4096);
  int4* records = (int4*)alloc((size_t)NT * 16);
  int* risky = (int*)alloc((size_t)NT * 4);
  int* perm1 = (int*)alloc((size_t)NT * 4);
  float* pw1 = (float*)alloc((size_t)NT * 4);
  int* perm2 = (int*)alloc((size_t)NT * 4);
  float* pw2 = (float*)alloc((size_t)NT * 4);
  int4* table1 = (int4*)alloc(1024 * 16);
  int4* table2 = (int4*)alloc(1024 * 16);
  float* wgn = (float*)alloc(256 * 64 * 4);
  unsigned short* WeT = (unsigned short*)alloc((size_t)NE * 256 * 256 * 2);
  unsigned short* xbf = nullptr;
  int use_xbf = 0;
  if (off + (size_t)NT * 256 * 2 <= ws_size) {
    xbf = (unsigned short*)alloc((size_t)NT * 256 * 2);
    use_xbf = 1;
  }

  hipMemsetAsync(ctrl, 0, 4096, stream);
  prep_w<<<64, 256, 0, stream>>>(Wg, Wn, wgn);
  prep_wet<<<dim3(32, 64), 256, 0, stream>>>(We, WeT);
  gate_kernel<<<NT / 64, 256, 0, stream>>>(x, wgn, nvec, records, risky, ctrl, xbf, use_xbf);
  fixup_kernel<<<64, 64, 0, stream>>>(x, wgn, nvec, records, risky, ctrl);
  scan_kernel<<<1, 64, 0, stream>>>(ctrl, table1, table2);
  scatter_kernel<<<NT / 256, 256, 0, stream>>>(records, ctrl, perm1, pw1, perm2, pw2);
  expert_kernel<<<dim3(544, 2), 256, 0, stream>>>(x, xbf, use_xbf, WeT, be, perm1, pw1, table1,
                                                  ctrl + C_TC1, out, 0);
  expert_kernel<<<dim3(544, 2), 256, 0, stream>>>(x, xbf, use_xbf, WeT, be, perm2, pw2, table2,
                                                  ctrl + C_TC2, out, 1);
}

// Round 2
// 389.402 us; speedup vs baseline: 1.2131x; 1.2131x over previous
//
#include <hip/hip_runtime.h>

#define NT 65536
#define DM 256
#define NE 32

typedef __attribute__((ext_vector_type(8))) short v8bf;
typedef __attribute__((ext_vector_type(4))) float v4f;

// ctrl block offsets (ints)
#define C_RISKY 0
#define C_TC1 1
#define C_TC2 2
#define C_HIST1 8
#define C_HIST2 40
#define C_CUR1 72
#define C_CUR2 104

__device__ __forceinline__ unsigned short f2bf(float f) {
  union { float f; unsigned u; } v; v.f = f;
  unsigned r = v.u + 0x7FFFu + ((v.u >> 16) & 1u);  // RNE
  return (unsigned short)(r >> 16);
}

// Gate weights: fp32 wgn[k][64] (fixup) + bf16 B^T wgnb[col][k] (MFMA).
__global__ __launch_bounds__(256) void prep_w(const float* __restrict__ Wg,
                                              const float* __restrict__ Wn,
                                              float* __restrict__ wgn,
                                              unsigned short* __restrict__ wgnb) {
  int i = blockIdx.x * 256 + threadIdx.x;
  if (i < 256 * 64) {
    int k = i >> 6, c = i & 63;
    float v = (c < 32) ? Wg[k * 32 + c] : Wn[k * 32 + (c - 32)];
    wgn[i] = v;
    wgnb[c * 256 + k] = f2bf(v);
  }
}

// WeT[e][h][d] = bf16(We[e][d][h]) — K-contiguous B^T layout for MFMA B-frags.
__global__ __launch_bounds__(256) void prep_wet(const float* __restrict__ We,
                                                unsigned short* __restrict__ WeT) {
  __shared__ float t[32][33];
  int e = blockIdx.x;
  int d0 = (blockIdx.y >> 3) * 32, h0 = (blockIdx.y & 7) * 32;
  int tx = threadIdx.x & 31, ty = threadIdx.x >> 5;
  const float* src = We + ((size_t)e * 256 + d0) * 256 + h0;
#pragma unroll
  for (int r = 0; r < 4; ++r) t[ty + r * 8][tx] = src[(size_t)(ty + r * 8) * 256 + tx];
  __syncthreads();
  unsigned short* dst = WeT + ((size_t)e * 256 + h0) * 256 + d0;
#pragma unroll
  for (int r = 0; r < 4; ++r) dst[(size_t)(ty + r * 8) * 256 + tx] = f2bf(t[tx][ty + r * 8]);
}

// Gate v2: bf16 MFMA GEMM H=[xWg | xWn] (BM=128, BN=64, K=256), epilogue does
// softplus + top-3 + margin-flag. Also emits bf16 copy of x for expert passes.
__global__ __launch_bounds__(256) void gate_kernel(const float* __restrict__ x,
                                                   const unsigned short* __restrict__ wgnb,
                                                   const float* __restrict__ nvec,
                                                   int4* __restrict__ records,
                                                   int* __restrict__ risky,
                                                   int* __restrict__ ctrl,
                                                   unsigned short* __restrict__ xbf,
                                                   int use_xbf) {
  __shared__ __align__(16) union {
    struct { short Al[128 * 72]; short Bl[64 * 72]; } t;
    float H[128 * 67];
  } sm;
  __shared__ float nvs[32];
  __shared__ int lh[64];
  int tid = threadIdx.x;
  if (tid < 64) lh[tid] = 0;
  if (tid < 32) nvs[tid] = nvec[tid];
  int t0 = blockIdx.x * 128;
  int lane = tid & 63, wid = tid >> 6;
  int wm = wid * 32;  // 2 m-tiles of 16 per wave
  int lm = lane & 15, lk = (lane >> 4) * 8;
  v4f acc[2][4];
  v4f zero = {0.f, 0.f, 0.f, 0.f};
#pragma unroll
  for (int mi = 0; mi < 2; ++mi)
#pragma unroll
    for (int ni = 0; ni < 4; ++ni) acc[mi][ni] = zero;
  for (int k0 = 0; k0 < 256; k0 += 64) {
    __syncthreads();
#pragma unroll
    for (int j = 0; j < 4; ++j) {  // A: 128 rows x 64 k
      int idx = tid + 256 * j;
      int row = idx >> 3, kc = idx & 7;
      const float4* s = (const float4*)(x + ((size_t)(t0 + row) * 256 + k0 + kc * 8));
      float4 a = s[0], b = s[1];
      union { v8bf v; unsigned short u[8]; uint4 q; } p;
      p.u[0] = f2bf(a.x); p.u[1] = f2bf(a.y); p.u[2] = f2bf(a.z); p.u[3] = f2bf(a.w);
      p.u[4] = f2bf(b.x); p.u[5] = f2bf(b.y); p.u[6] = f2bf(b.z); p.u[7] = f2bf(b.w);
      *(v8bf*)(sm.t.Al + row * 72 + kc * 8) = p.v;
      if (use_xbf) *(uint4*)(xbf + ((size_t)(t0 + row) * 256 + k0 + kc * 8)) = p.q;
    }
#pragma unroll
    for (int j = 0; j < 2; ++j) {  // B: 64 cols x 64 k
      int idx = tid + 256 * j;
      int col = idx >> 3, kc = idx & 7;
      uint4 w = *(const uint4*)(wgnb + ((size_t)col * 256 + k0 + kc * 8));
      *(uint4*)(sm.t.Bl + col * 72 + kc * 8) = w;
    }
    __syncthreads();
#pragma unroll
    for (int ks = 0; ks < 64; ks += 32) {
      v8bf af[2], bfr[4];
#pragma unroll
      for (int mi = 0; mi < 2; ++mi)
        af[mi] = *(const v8bf*)(sm.t.Al + (wm + mi * 16 + lm) * 72 + ks + lk);
#pragma unroll
      for (int ni = 0; ni < 4; ++ni)
        bfr[ni] = *(const v8bf*)(sm.t.Bl + (ni * 16 + lm) * 72 + ks + lk);
#pragma unroll
      for (int mi = 0; mi < 2; ++mi)
#pragma unroll
        for (int ni = 0; ni < 4; ++ni)
          acc[mi][ni] = __builtin_amdgcn_mfma_f32_16x16x32_bf16(af[mi], bfr[ni], acc[mi][ni], 0, 0, 0);
    }
  }
  __syncthreads();  // Al/Bl dead; reuse as H
  int cg = lane & 15, rg = lane >> 4;
#pragma unroll
  for (int mi = 0; mi < 2; ++mi)
#pragma unroll
    for (int r = 0; r < 4; ++r) {
      int row = wm + mi * 16 + rg * 4 + r;
#pragma unroll
      for (int ni = 0; ni < 4; ++ni) sm.H[row * 67 + ni * 16 + cg] = acc[mi][ni][r];
    }
  __syncthreads();
  if (tid < 128) {
    int t = t0 + tid;
    float v1 = -3e38f, v2 = -3e38f, v3 = -3e38f;
    int i1 = 0, i2 = 0;
#pragma unroll 4
    for (int e = 0; e < 32; ++e) {
      float g = sm.H[tid * 67 + e];
      float n = sm.H[tid * 67 + 32 + e];
      float sp = fmaxf(n, 0.f) + log1pf(expf(-fabsf(n)));
      float he = fmaf(nvs[e], sp, g);
      if (he > v1) { v3 = v2; v2 = v1; i2 = i1; v1 = he; i1 = e; }
      else if (he > v2) { v3 = v2; v2 = he; i2 = e; }
      else if (he > v3) v3 = he;
    }
    float w1v = 1.f / (1.f + expf(v2 - v1));
    float w2v = 1.f / (1.f + expf(v1 - v2));
    records[t] = make_int4(i1, i2, __float_as_int(w1v), __float_as_int(w2v));
    atomicAdd(&lh[i1], 1);
    atomicAdd(&lh[32 + i2], 1);
    if (v2 - v3 < 2e-2f) {  // ~10 sigma of bf16-GEMM error on the gap
      int p = atomicAdd(&ctrl[C_RISKY], 1);
      risky[p] = t;
    }
  }
  __syncthreads();
  if (tid < 32) atomicAdd(&ctrl[C_HIST1 + tid], lh[tid]);
  else if (tid < 64) atomicAdd(&ctrl[C_HIST2 + (tid - 32)], lh[tid]);
}

// fp64 recompute of gating for risky tokens; patches records + histograms.
// One wave per token, 1024 waves in flight.
__global__ __launch_bounds__(256) void fixup_kernel(const float* __restrict__ x,
                                                    const float* __restrict__ wgn,
                                                    const float* __restrict__ nvec,
                                                    int4* __restrict__ records,
                                                    const int* __restrict__ risky,
                                                    int* __restrict__ ctrl) {
  int cnt = ctrl[C_RISKY];
  int lane = threadIdx.x & 63, wid = threadIdx.x >> 6;
  for (int r = blockIdx.x * 4 + wid; r < cnt; r += gridDim.x * 4) {
    int t = __builtin_amdgcn_readfirstlane(risky[r]);
    const float* xr = x + (size_t)t * 256;
    double a0 = 0.0, a1 = 0.0, a2 = 0.0, a3 = 0.0;
    for (int k = 0; k < 256; k += 4) {
      float4 xv = *(const float4*)(xr + k);
      a0 = fma((double)xv.x, (double)wgn[(k + 0) * 64 + lane], a0);
      a1 = fma((double)xv.y, (double)wgn[(k + 1) * 64 + lane], a1);
      a2 = fma((double)xv.z, (double)wgn[(k + 2) * 64 + lane], a2);
      a3 = fma((double)xv.w, (double)wgn[(k + 3) * 64 + lane], a3);
    }
    double acc = (a0 + a1) + (a2 + a3);
    double sv = __shfl(acc, lane + 32);
    double H;
    if (lane < 32) {
      double sp = fmax(sv, 0.0) + log1p(exp(-fabs(sv)));
      H = acc + (double)nvec[lane] * sp;
    } else
      H = -1e300;
    double v = H; int idx = lane;
#pragma unroll
    for (int off = 32; off >= 1; off >>= 1) {
      double ov = __shfl_xor(v, off); int oi = __shfl_xor(idx, off);
      if (ov > v || (ov == v && oi < idx)) { v = ov; idx = oi; }
    }
    int i1 = idx; double v1 = v;
    v = (lane == i1) ? -1e300 : H; idx = lane;
#pragma unroll
    for (int off = 32; off >= 1; off >>= 1) {
      double ov = __shfl_xor(v, off); int oi = __shfl_xor(idx, off);
      if (ov > v || (ov == v && oi < idx)) { v = ov; idx = oi; }
    }
    int i2 = idx; double v2 = v;
    if (lane == 0) {
      float w1v = (float)(1.0 / (1.0 + exp(v2 - v1)));
      float w2v = (float)(1.0 / (1.0 + exp(v1 - v2)));
      int4 old = records[t];
      if (old.x != i1) { atomicSub(&ctrl[C_HIST1 + old.x], 1); atomicAdd(&ctrl[C_HIST1 + i1], 1); }
      if (old.y != i2) { atomicSub(&ctrl[C_HIST2 + old.y], 1); atomicAdd(&ctrl[C_HIST2 + i2], 1); }
      records[t] = make_int4(i1, i2, __float_as_int(w1v), __float_as_int(w2v));
    }
  }
}

// Segment offsets + per-tile work tables (BM=128 tiles per expert segment).
__global__ __launch_bounds__(64) void scan_kernel(int* __restrict__ ctrl,
                                                  int4* __restrict__ table1,
                                                  int4* __restrict__ table2) {
  __shared__ int so1[32], so2[32], tp1[32], tp2[32];
  int tid = threadIdx.x;
  if (tid == 0) {
    int o = 0, tp = 0;
    for (int e = 0; e < 32; ++e) {
      so1[e] = o; tp1[e] = tp;
      int c = ctrl[C_HIST1 + e];
      o += c; tp += (c + 127) >> 7;
    }
    ctrl[C_TC1] = tp;
    o = 0; tp = 0;
    for (int e = 0; e < 32; ++e) {
      so2[e] = o; tp2[e] = tp;
      int c = ctrl[C_HIST2 + e];
      o += c; tp += (c + 127) >> 7;
    }
    ctrl[C_TC2] = tp;
  }
  __syncthreads();
  if (tid < 32) {
    int e = tid;
    ctrl[C_CUR1 + e] = so1[e];
    int c = ctrl[C_HIST1 + e];
    int nt = (c + 127) >> 7;
    for (int m = 0; m < nt; ++m)
      table1[tp1[e] + m] = make_int4(e, so1[e] + m * 128, min(128, c - m * 128), 0);
  } else if (tid < 64) {
    int e = tid - 32;
    ctrl[C_CUR2 + e] = so2[e];
    int c = ctrl[C_HIST2 + e];
    int nt = (c + 127) >> 7;
    for (int m = 0; m < nt; ++m)
      table2[tp2[e] + m] = make_int4(e, so2[e] + m * 128, min(128, c - m * 128), 0);
  }
}

// Bucket tokens by expert (intra-block rank + block base).
__global__ __launch_bounds__(256) void scatter_kernel(const int4* __restrict__ records,
                                                      int* __restrict__ ctrl,
                                                      int* __restrict__ perm1, float* __restrict__ pw1,
                                                      int* __restrict__ perm2, float* __restrict__ pw2) {
  __shared__ int lh1[32], lh2[32], b1[32], b2[32];
  int tid = threadIdx.x;
  if (tid < 32) { lh1[tid] = 0; lh2[tid] = 0; }
  __syncthreads();
  int t = blockIdx.x * 256 + tid;
  int4 rec = records[t];
  int r1 = atomicAdd(&lh1[rec.x], 1);
  int r2 = atomicAdd(&lh2[rec.y], 1);
  __syncthreads();
  if (tid < 32) {
    b1[tid] = atomicAdd(&ctrl[C_CUR1 + tid], lh1[tid]);
    b2[tid] = atomicAdd(&ctrl[C_CUR2 + tid], lh2[tid]);
  }
  __syncthreads();
  int s1 = b1[rec.x] + r1; perm1[s1] = t; pw1[s1] = __int_as_float(rec.z);
  int s2 = b2[rec.y] + r2; perm2[s2] = t; pw2[s2] = __int_as_float(rec.w);
}

// Grouped GEMM: out[tok,:] (+)= w * (x[tok,:] @ We[e]) + w*be[e,:], bf16 MFMA.
__global__ __launch_bounds__(256) void expert_kernel(const float* __restrict__ x,
                                                     const unsigned short* __restrict__ xbf,
                                                     int use_xbf,
                                                     const unsigned short* __restrict__ WeT,
                                                     const float* __restrict__ be,
                                                     const int* __restrict__ perm,
                                                     const float* __restrict__ pw,
                                                     const int4* __restrict__ table,
                                                     const int* __restrict__ tcp,
                                                     float* __restrict__ out,
                                                     int accumulate) {
  int nt = *tcp;
  if (blockIdx.x >= nt) return;
  int4 ent = table[blockIdx.x];
  int e = ent.x, sbase = ent.y, rows = ent.z;
  int n0 = blockIdx.y * 128;
  __shared__ __align__(16) short Al[128 * 72];
  __shared__ __align__(16) short Bl[128 * 72];
  __shared__ int toks[128];
  int tid = threadIdx.x;
  if (tid < 128) toks[tid] = perm[sbase + min(tid, rows - 1)];
  v4f acc[4][4];
  v4f zero = {0.f, 0.f, 0.f, 0.f};
#pragma unroll
  for (int mi = 0; mi < 4; ++mi)
#pragma unroll
    for (int ni = 0; ni < 4; ++ni) acc[mi][ni] = zero;
  int lane = tid & 63, wid = tid >> 6;
  int wm = (wid & 1) * 64, wn = (wid >> 1) * 64;
  int lm = lane & 15, lk = (lane >> 4) * 8;
  for (int k0 = 0; k0 < 256; k0 += 64) {
    __syncthreads();
#pragma unroll
    for (int j = 0; j < 4; ++j) {
      int idx = tid + 256 * j;
      int row = idx >> 3, kc = idx & 7;
      if (use_xbf) {
        uint4 v = *(const uint4*)(xbf + ((size_t)toks[row] * 256 + k0 + kc * 8));
        *(uint4*)(Al + row * 72 + kc * 8) = v;
      } else {
        const float4* s = (const float4*)(x + ((size_t)toks[row] * 256 + k0 + kc * 8));
        float4 a = s[0], b = s[1];
        union { v8bf v; unsigned short u[8]; } p;
        p.u[0] = f2bf(a.x); p.u[1] = f2bf(a.y); p.u[2] = f2bf(a.z); p.u[3] = f2bf(a.w);
        p.u[4] = f2bf(b.x); p.u[5] = f2bf(b.y); p.u[6] = f2bf(b.z); p.u[7] = f2bf(b.w);
        *(v8bf*)(Al + row * 72 + kc * 8) = p.v;
      }
      uint4 w = *(const uint4*)(WeT + (((size_t)e * 256 + n0 + row) * 256 + k0 + kc * 8));
      *(uint4*)(Bl + row * 72 + kc * 8) = w;
    }
    __syncthreads();
#pragma unroll
    for (int ks = 0; ks < 64; ks += 32) {
      v8bf af[4], bfr[4];
#pragma unroll
      for (int mi = 0; mi < 4; ++mi)
        af[mi] = *(const v8bf*)(Al + (wm + mi * 16 + lm) * 72 + ks + lk);
#pragma unroll
      for (int ni = 0; ni < 4; ++ni)
        bfr[ni] = *(const v8bf*)(Bl + (wn + ni * 16 + lm) * 72 + ks + lk);
#pragma unroll
      for (int mi = 0; mi < 4; ++mi)
#pragma unroll
        for (int ni = 0; ni < 4; ++ni)
          acc[mi][ni] = __builtin_amdgcn_mfma_f32_16x16x32_bf16(af[mi], bfr[ni], acc[mi][ni], 0, 0, 0);
    }
  }
  int cg = lane & 15, rg = lane >> 4;
#pragma unroll
  for (int mi = 0; mi < 4; ++mi) {
#pragma unroll
    for (int r = 0; r < 4; ++r) {
      int srow = wm + mi * 16 + rg * 4 + r;
      if (srow < rows) {
        int slot = sbase + srow;
        int tok = perm[slot];
        float w = pw[slot];
        size_t ob = (size_t)tok * 256;
#pragma unroll
        for (int ni = 0; ni < 4; ++ni) {
          int c = n0 + wn + ni * 16 + cg;
          float v = acc[mi][ni][r] * w + w * be[e * 256 + c];
          if (accumulate) out[ob + c] += v;
          else out[ob + c] = v;
        }
      }
    }
  }
}

extern "C" void kernel_launch(void* const* d_in, const int* in_sizes, int n_in,
                              void* d_out, int out_size, void* d_ws, size_t ws_size,
                              hipStream_t stream) {
  const float* x = (const float*)d_in[0];
  const float* Wg = (const float*)d_in[1];
  const float* Wn = (const float*)d_in[2];
  const float* We = (const float*)d_in[3];
  const float* be = (const float*)d_in[4];
  const float* nvec = (const float*)d_in[5];
  float* out = (float*)d_out;
  char* ws = (char*)d_ws;
  size_t off = 0;
  auto alloc = [&](size_t bytes) -> void* {
    void* p = ws + off;
    off = (off + bytes + 255) & ~(size_t)255;
    return p;
  };
  int* ctrl = (int*)alloc(4096);
  int4* records = (int4*)alloc((size_t)NT * 16);
  int* risky = (int*)alloc((size_t)NT * 4);
  int* perm1 = (int*)alloc((size_t)NT * 4);
  float* pw1 = (float*)alloc((size_t)NT * 4);
  int* perm2 = (int*)alloc((size_t)NT * 4);
  float* pw2 = (float*)alloc((size_t)NT * 4);
  int4* table1 = (int4*)alloc(1024 * 16);
  int4* table2 = (int4*)alloc(1024 * 16);
  float* wgn = (float*)alloc(256 * 64 * 4);
  unsigned short* wgnb = (unsigned short*)alloc(64 * 256 * 2);
  unsigned short* WeT = (unsigned short*)alloc((size_t)NE * 256 * 256 * 2);
  unsigned short* xbf = nullptr;
  int use_xbf = 0;
  if (off + (size_t)NT * 256 * 2 <= ws_size) {
    xbf = (unsigned short*)alloc((size_t)NT * 256 * 2);
    use_xbf = 1;
  }

  hipMemsetAsync(ctrl, 0, 4096, stream);
  prep_w<<<64, 256, 0, stream>>>(Wg, Wn, wgn, wgnb);
  prep_wet<<<dim3(32, 64), 256, 0, stream>>>(We, WeT);
  gate_kernel<<<NT / 128, 256, 0, stream>>>(x, wgnb, nvec, records, risky, ctrl, xbf, use_xbf);
  fixup_kernel<<<256, 256, 0, stream>>>(x, wgn, nvec, records, risky, ctrl);
  scan_kernel<<<1, 64, 0, stream>>>(ctrl, table1, table2);
  scatter_kernel<<<NT / 256, 256, 0, stream>>>(records, ctrl, perm1, pw1, perm2, pw2);
  expert_kernel<<<dim3(544, 2), 256, 0, stream>>>(x, xbf, use_xbf, WeT, be, perm1, pw1, table1,
                                                  ctrl + C_TC1, out, 0);
  expert_kernel<<<dim3(544, 2), 256, 0, stream>>>(x, xbf, use_xbf, WeT, be, perm2, pw2, table2,
                                                  ctrl + C_TC2, out, 1);
}